// Round 1
// baseline (191.248 us; speedup 1.0000x reference)
//
#include <hip/hip_runtime.h>
#include <stdint.h>

#define IN_DIM   4096
#define OUT_DIM  4096
#define TPB      256
#define TOKS     8        // tokens per block; LDS layout = 4 bf16x2 pairs per column

// pack two fp32 -> bf16x2 dword (lo16 = a, hi16 = b), round-to-nearest-even
__device__ __forceinline__ uint32_t pack_bf16x2(float a, float b) {
    uint32_t ua = __float_as_uint(a);
    uint32_t ub = __float_as_uint(b);
    ua = (ua + 0x7fffu + ((ua >> 16) & 1u)) >> 16;
    ub = (ub + 0x7fffu + ((ub >> 16) & 1u)) & 0xffff0000u;
    return ub | ua;
}

// Stage 8 tokens of x (fp32, row-major [token][IN_DIM]) into LDS as bf16x2,
// column-major: xs[col*4 + pair], pair p holds tokens (2p, 2p+1).
// Lane mapping: pair = lane>>4, c4 = (lane&15) + 16*wave + 64*it.
// Writes are rotated per-lane ((jj+rot)&3) so banks spread 2-way (free).
__device__ __forceinline__ void stage_x_tile(const float* __restrict__ x,
                                             size_t tb, uint32_t* xs,
                                             int lane, int wave) {
    const int tp  = lane >> 4;          // token pair 0..3
    const int rot = (lane >> 1) & 3;    // write-order rotation
    const float* xa = x + (tb + 2 * (size_t)tp) * IN_DIM;
    const float* xb = xa + IN_DIM;
    #pragma unroll 4
    for (int it = 0; it < IN_DIM / 4 / 64; ++it) {   // 16 iterations
        const int c4 = (lane & 15) + 16 * wave + 64 * it;   // float4 column group
        const float4 a = *reinterpret_cast<const float4*>(xa + 4 * c4);
        const float4 b = *reinterpret_cast<const float4*>(xb + 4 * c4);
        const uint32_t d0 = pack_bf16x2(a.x, b.x);
        const uint32_t d1 = pack_bf16x2(a.y, b.y);
        const uint32_t d2 = pack_bf16x2(a.z, b.z);
        const uint32_t d3 = pack_bf16x2(a.w, b.w);
        // branchless rotate-left by rot: u_jj = d[(jj+rot)&3] (no runtime array idx)
        const uint32_t t0 = (rot & 2) ? d2 : d0;
        const uint32_t t1 = (rot & 2) ? d3 : d1;
        const uint32_t t2 = (rot & 2) ? d0 : d2;
        const uint32_t t3 = (rot & 2) ? d1 : d3;
        const uint32_t u0 = (rot & 1) ? t1 : t0;
        const uint32_t u1 = (rot & 1) ? t2 : t1;
        const uint32_t u2 = (rot & 1) ? t3 : t2;
        const uint32_t u3 = (rot & 1) ? t0 : t3;
        const int cb = 4 * c4;
        xs[(cb + ((0 + rot) & 3)) * 4 + tp] = u0;
        xs[(cb + ((1 + rot) & 3)) * 4 + tp] = u1;
        xs[(cb + ((2 + rot) & 3)) * 4 + tp] = u2;
        xs[(cb + ((3 + rot) & 3)) * 4 + tp] = u3;
    }
}

// Build ELL metadata: ell[k*OUT_DIM + r] = (bf16(values) << 16) | col
// (zero-padded rows -> val=+0, col=0: harmless).
__global__ void build_ell(const float* __restrict__ values,
                          const int* __restrict__ row_offs,
                          const int* __restrict__ col_idx,
                          uint32_t* __restrict__ ell, int kmax) {
    const int r = blockIdx.x * blockDim.x + threadIdx.x;
    if (r >= OUT_DIM) return;
    const int beg = row_offs[r];
    const int end = row_offs[r + 1];
    for (int k = 0; k < kmax; ++k) {
        uint32_t u = 0;
        if (beg + k < end) {
            const uint32_t c = (uint32_t)col_idx[beg + k];
            uint32_t vb = __float_as_uint(values[beg + k]);
            vb = (vb + 0x7fffu + ((vb >> 16) & 1u)) & 0xffff0000u;
            u = vb | c;
        }
        ell[(size_t)k * OUT_DIM + r] = u;
    }
}

__global__ __launch_bounds__(TPB, 2)
void spmm_ell(const float* __restrict__ x, const uint32_t* __restrict__ ell,
              float* __restrict__ y, int kmax) {
    __shared__ __align__(16) uint32_t xs[IN_DIM * (TOKS / 2)];   // 64 KB
    const int tid  = threadIdx.x;
    const size_t tb = (size_t)blockIdx.x * TOKS;

    stage_x_tile(x, tb, xs, tid & 63, tid >> 6);
    __syncthreads();

    #pragma unroll 1
    for (int chunk = 0; chunk < OUT_DIM / TPB; ++chunk) {
        const int r = chunk * TPB + tid;
        float acc[TOKS] = {0.f, 0.f, 0.f, 0.f, 0.f, 0.f, 0.f, 0.f};
        const uint32_t* ep = ell + r;
        #pragma unroll 4
        for (int k = 0; k < kmax; ++k) {
            const uint32_t e = ep[(size_t)k * OUT_DIM];      // coalesced 512B/wave
            const float v = __uint_as_float(e);               // col bits in mantissa tail: rel err < 2^-11
            const uint32_t c = e & 0xffffu;
            const uint4 d = *reinterpret_cast<const uint4*>(&xs[4 * c]);  // ds_read_b128: 8 tokens
            acc[0] = fmaf(v, __uint_as_float(d.x << 16), acc[0]);
            acc[1] = fmaf(v, __uint_as_float(d.x & 0xffff0000u), acc[1]);
            acc[2] = fmaf(v, __uint_as_float(d.y << 16), acc[2]);
            acc[3] = fmaf(v, __uint_as_float(d.y & 0xffff0000u), acc[3]);
            acc[4] = fmaf(v, __uint_as_float(d.z << 16), acc[4]);
            acc[5] = fmaf(v, __uint_as_float(d.z & 0xffff0000u), acc[5]);
            acc[6] = fmaf(v, __uint_as_float(d.w << 16), acc[6]);
            acc[7] = fmaf(v, __uint_as_float(d.w & 0xffff0000u), acc[7]);
        }
        #pragma unroll
        for (int t = 0; t < TOKS; ++t)
            y[(tb + t) * OUT_DIM + r] = acc[t];
    }
}

// Fallback if d_ws is too small for ELL: read CSR directly (fp32 values).
__global__ __launch_bounds__(TPB, 2)
void spmm_csr(const float* __restrict__ x, const float* __restrict__ values,
              const int* __restrict__ row_offs, const int* __restrict__ col_idx,
              float* __restrict__ y) {
    __shared__ __align__(16) uint32_t xs[IN_DIM * (TOKS / 2)];
    const int tid  = threadIdx.x;
    const size_t tb = (size_t)blockIdx.x * TOKS;

    stage_x_tile(x, tb, xs, tid & 63, tid >> 6);
    __syncthreads();

    #pragma unroll 1
    for (int chunk = 0; chunk < OUT_DIM / TPB; ++chunk) {
        const int r = chunk * TPB + tid;
        float acc[TOKS] = {0.f, 0.f, 0.f, 0.f, 0.f, 0.f, 0.f, 0.f};
        int k = row_offs[r];
        const int ke = row_offs[r + 1];
        for (; k < ke; ++k) {
            const float v = values[k];
            const uint32_t c = (uint32_t)col_idx[k];
            const uint4 d = *reinterpret_cast<const uint4*>(&xs[4 * c]);
            acc[0] = fmaf(v, __uint_as_float(d.x << 16), acc[0]);
            acc[1] = fmaf(v, __uint_as_float(d.x & 0xffff0000u), acc[1]);
            acc[2] = fmaf(v, __uint_as_float(d.y << 16), acc[2]);
            acc[3] = fmaf(v, __uint_as_float(d.y & 0xffff0000u), acc[3]);
            acc[4] = fmaf(v, __uint_as_float(d.z << 16), acc[4]);
            acc[5] = fmaf(v, __uint_as_float(d.z & 0xffff0000u), acc[5]);
            acc[6] = fmaf(v, __uint_as_float(d.w << 16), acc[6]);
            acc[7] = fmaf(v, __uint_as_float(d.w & 0xffff0000u), acc[7]);
        }
        #pragma unroll
        for (int t = 0; t < TOKS; ++t)
            y[(tb + t) * OUT_DIM + r] = acc[t];
    }
}

extern "C" void kernel_launch(void* const* d_in, const int* in_sizes, int n_in,
                              void* d_out, int out_size, void* d_ws, size_t ws_size,
                              hipStream_t stream) {
    const float* x        = (const float*)d_in[0];
    const float* values   = (const float*)d_in[1];
    const int*   row_offs = (const int*)d_in[2];
    const int*   col_idx  = (const int*)d_in[3];
    float* y = (float*)d_out;

    const int nnz  = in_sizes[1];
    const int rows = in_sizes[2] - 1;              // 4096
    const int ntok = in_sizes[0] / IN_DIM;         // 8192
    const int kmax = nnz / rows + ((nnz % rows) ? 1 : 0);   // 41

    dim3 grid(ntok / TOKS), block(TPB);
    const size_t ell_bytes = (size_t)kmax * OUT_DIM * sizeof(uint32_t);
    if (ws_size >= ell_bytes) {
        uint32_t* ell = (uint32_t*)d_ws;
        build_ell<<<dim3((rows + TPB - 1) / TPB), dim3(TPB), 0, stream>>>(
            values, row_offs, col_idx, ell, kmax);
        spmm_ell<<<grid, block, 0, stream>>>(x, ell, y, kmax);
    } else {
        spmm_csr<<<grid, block, 0, stream>>>(x, values, row_offs, col_idx, y);
    }
}

// Round 2
// 126.791 us; speedup vs baseline: 1.5084x; 1.5084x over previous
//
#include <hip/hip_runtime.h>
#include <stdint.h>

#define IN_DIM   4096
#define OUT_DIM  4096
#define TPB      512
#define TOKS     8        // tokens per block; LDS = 4 bf16x2 pairs per column

// pack two fp32 -> bf16x2 dword (lo16 = a, hi16 = b), round-to-nearest-even
__device__ __forceinline__ uint32_t pack_bf16x2(float a, float b) {
    uint32_t ua = __float_as_uint(a);
    uint32_t ub = __float_as_uint(b);
    ua = (ua + 0x7fffu + ((ua >> 16) & 1u)) >> 16;
    ub = (ub + 0x7fffu + ((ub >> 16) & 1u)) & 0xffff0000u;
    return ub | ua;
}

// Stage 8 tokens of x (fp32, [token][IN_DIM]) into LDS as bf16x2, column-major:
// xs[col*4 + pair]; pair p holds tokens (2p, 2p+1).
// Per-lane write rotation keeps staging writes ~2-way banked (free).
__device__ __forceinline__ void stage_x_tile(const float* __restrict__ x,
                                             size_t tb, uint32_t* xs, int tid) {
    const int lane = tid & 63;
    const int wave = tid >> 6;          // 0..7
    const int tp   = lane >> 4;         // token pair 0..3
    const int rot  = (lane >> 1) & 3;   // write-order rotation
    const float* xa = x + (tb + 2 * (size_t)tp) * IN_DIM;
    const float* xb = xa + IN_DIM;
    #pragma unroll
    for (int it = 0; it < IN_DIM / 4 / 128; ++it) {   // 8 iterations
        const int c4 = (lane & 15) + 16 * wave + 128 * it;   // float4 column group
        const float4 a = *reinterpret_cast<const float4*>(xa + 4 * c4);
        const float4 b = *reinterpret_cast<const float4*>(xb + 4 * c4);
        const uint32_t d0 = pack_bf16x2(a.x, b.x);
        const uint32_t d1 = pack_bf16x2(a.y, b.y);
        const uint32_t d2 = pack_bf16x2(a.z, b.z);
        const uint32_t d3 = pack_bf16x2(a.w, b.w);
        // branchless rotate-left by rot (no runtime array indexing -> no scratch)
        const uint32_t t0 = (rot & 2) ? d2 : d0;
        const uint32_t t1 = (rot & 2) ? d3 : d1;
        const uint32_t t2 = (rot & 2) ? d0 : d2;
        const uint32_t t3 = (rot & 2) ? d1 : d3;
        const uint32_t u0 = (rot & 1) ? t1 : t0;
        const uint32_t u1 = (rot & 1) ? t2 : t1;
        const uint32_t u2 = (rot & 1) ? t3 : t2;
        const uint32_t u3 = (rot & 1) ? t0 : t3;
        const int cb = 4 * c4;
        xs[(cb + ((0 + rot) & 3)) * 4 + tp] = u0;
        xs[(cb + ((1 + rot) & 3)) * 4 + tp] = u1;
        xs[(cb + ((2 + rot) & 3)) * 4 + tp] = u2;
        xs[(cb + ((3 + rot) & 3)) * 4 + tp] = u3;
    }
}

// ELL metadata: ell[k*OUT_DIM + r] = (bf16(values) << 16) | col ; zero padded.
// One thread per (r, k) element.
__global__ void build_ell(const float* __restrict__ values,
                          const int* __restrict__ row_offs,
                          const int* __restrict__ col_idx,
                          uint32_t* __restrict__ ell, int kalloc) {
    const int idx = blockIdx.x * blockDim.x + threadIdx.x;
    const int r = idx & (OUT_DIM - 1);
    const int k = idx >> 12;            // log2(OUT_DIM)
    if (k >= kalloc) return;
    const int beg = row_offs[r];
    const int end = row_offs[r + 1];
    uint32_t u = 0;
    if (beg + k < end) {
        const uint32_t c = (uint32_t)col_idx[beg + k];
        uint32_t vb = __float_as_uint(values[beg + k]);
        vb = (vb + 0x7fffu + ((vb >> 16) & 1u)) & 0xffff0000u;
        u = vb | c;
    }
    ell[(size_t)k * OUT_DIM + r] = u;
}

// 8 MACs from one bf16x2-packed uint4 (8 tokens) against value e
// (value used with col bits in mantissa tail: rel err < 2^-11).
#define FMA8(E, D)                                                    \
    do {                                                              \
        const float v_ = __uint_as_float(E);                          \
        acc0 = fmaf(v_, __uint_as_float((D).x << 16), acc0);          \
        acc1 = fmaf(v_, __uint_as_float((D).x & 0xffff0000u), acc1);  \
        acc2 = fmaf(v_, __uint_as_float((D).y << 16), acc2);          \
        acc3 = fmaf(v_, __uint_as_float((D).y & 0xffff0000u), acc3);  \
        acc4 = fmaf(v_, __uint_as_float((D).z << 16), acc4);          \
        acc5 = fmaf(v_, __uint_as_float((D).z & 0xffff0000u), acc5);  \
        acc6 = fmaf(v_, __uint_as_float((D).w << 16), acc6);          \
        acc7 = fmaf(v_, __uint_as_float((D).w & 0xffff0000u), acc7);  \
    } while (0)

#define GATH(D, E) (D) = xs4[(E) & 0xffffu]

__global__ __launch_bounds__(TPB, 4)
void spmm_ell(const float* __restrict__ x, const uint32_t* __restrict__ ell,
              float* __restrict__ y, int ng) {
    __shared__ __align__(16) uint32_t xs[IN_DIM * (TOKS / 2)];   // 64 KB
    const int tid  = threadIdx.x;
    const size_t tb = (size_t)blockIdx.x * TOKS;

    stage_x_tile(x, tb, xs, tid);
    __syncthreads();
    const uint4* xs4 = reinterpret_cast<const uint4*>(xs);

    #pragma unroll 1
    for (int chunk = 0; chunk < OUT_DIM / TPB; ++chunk) {
        const int r = chunk * TPB + tid;
        float acc0 = 0.f, acc1 = 0.f, acc2 = 0.f, acc3 = 0.f;
        float acc4 = 0.f, acc5 = 0.f, acc6 = 0.f, acc7 = 0.f;
        const uint32_t* ep = ell + r;

        // ---- 2-deep software pipeline over k-groups of 4 (ng is even) ----
        // prologue: group0 -> (eA, dA), group1 -> eB
        uint32_t eA0 = ep[0 * (size_t)OUT_DIM], eA1 = ep[1 * (size_t)OUT_DIM];
        uint32_t eA2 = ep[2 * (size_t)OUT_DIM], eA3 = ep[3 * (size_t)OUT_DIM];
        uint4 dA0, dA1, dA2, dA3;
        GATH(dA0, eA0); GATH(dA1, eA1); GATH(dA2, eA2); GATH(dA3, eA3);
        uint32_t eB0 = ep[4 * (size_t)OUT_DIM], eB1 = ep[5 * (size_t)OUT_DIM];
        uint32_t eB2 = ep[6 * (size_t)OUT_DIM], eB3 = ep[7 * (size_t)OUT_DIM];
        uint4 dB0, dB1, dB2, dB3;
        const uint32_t* epn = ep + 8 * (size_t)OUT_DIM;

        #pragma unroll 1
        for (int g = 0; g < ng; g += 2) {
            // step g: compute (eA,dA); gather d for g+1 from eB; prefetch e(g+2)
            const uint32_t tA0 = epn[0 * (size_t)OUT_DIM], tA1 = epn[1 * (size_t)OUT_DIM];
            const uint32_t tA2 = epn[2 * (size_t)OUT_DIM], tA3 = epn[3 * (size_t)OUT_DIM];
            GATH(dB0, eB0); GATH(dB1, eB1); GATH(dB2, eB2); GATH(dB3, eB3);
            FMA8(eA0, dA0); FMA8(eA1, dA1); FMA8(eA2, dA2); FMA8(eA3, dA3);
            epn += 4 * (size_t)OUT_DIM;

            // step g+1: compute (eB,dB); gather d(g+2) from tA; prefetch e(g+3)
            const uint32_t tB0 = epn[0 * (size_t)OUT_DIM], tB1 = epn[1 * (size_t)OUT_DIM];
            const uint32_t tB2 = epn[2 * (size_t)OUT_DIM], tB3 = epn[3 * (size_t)OUT_DIM];
            GATH(dA0, tA0); GATH(dA1, tA1); GATH(dA2, tA2); GATH(dA3, tA3);
            FMA8(eB0, dB0); FMA8(eB1, dB1); FMA8(eB2, dB2); FMA8(eB3, dB3);
            epn += 4 * (size_t)OUT_DIM;

            eA0 = tA0; eA1 = tA1; eA2 = tA2; eA3 = tA3;   // e(g+2), its d in dA
            eB0 = tB0; eB1 = tB1; eB2 = tB2; eB3 = tB3;   // e(g+3)
        }

        y[(tb + 0) * OUT_DIM + r] = acc0;
        y[(tb + 1) * OUT_DIM + r] = acc1;
        y[(tb + 2) * OUT_DIM + r] = acc2;
        y[(tb + 3) * OUT_DIM + r] = acc3;
        y[(tb + 4) * OUT_DIM + r] = acc4;
        y[(tb + 5) * OUT_DIM + r] = acc5;
        y[(tb + 6) * OUT_DIM + r] = acc6;
        y[(tb + 7) * OUT_DIM + r] = acc7;
    }
}

// Fallback if d_ws too small for ELL: direct CSR (fp32 values).
__global__ __launch_bounds__(TPB, 4)
void spmm_csr(const float* __restrict__ x, const float* __restrict__ values,
              const int* __restrict__ row_offs, const int* __restrict__ col_idx,
              float* __restrict__ y) {
    __shared__ __align__(16) uint32_t xs[IN_DIM * (TOKS / 2)];
    const int tid  = threadIdx.x;
    const size_t tb = (size_t)blockIdx.x * TOKS;

    stage_x_tile(x, tb, xs, tid);
    __syncthreads();
    const uint4* xs4 = reinterpret_cast<const uint4*>(xs);

    #pragma unroll 1
    for (int chunk = 0; chunk < OUT_DIM / TPB; ++chunk) {
        const int r = chunk * TPB + tid;
        float acc0 = 0.f, acc1 = 0.f, acc2 = 0.f, acc3 = 0.f;
        float acc4 = 0.f, acc5 = 0.f, acc6 = 0.f, acc7 = 0.f;
        int k = row_offs[r];
        const int ke = row_offs[r + 1];
        for (; k < ke; ++k) {
            const uint32_t e = __float_as_uint(values[k]);
            const uint4 d = xs4[(uint32_t)col_idx[k]];
            FMA8(e, d);
        }
        y[(tb + 0) * OUT_DIM + r] = acc0;
        y[(tb + 1) * OUT_DIM + r] = acc1;
        y[(tb + 2) * OUT_DIM + r] = acc2;
        y[(tb + 3) * OUT_DIM + r] = acc3;
        y[(tb + 4) * OUT_DIM + r] = acc4;
        y[(tb + 5) * OUT_DIM + r] = acc5;
        y[(tb + 6) * OUT_DIM + r] = acc6;
        y[(tb + 7) * OUT_DIM + r] = acc7;
    }
}

extern "C" void kernel_launch(void* const* d_in, const int* in_sizes, int n_in,
                              void* d_out, int out_size, void* d_ws, size_t ws_size,
                              hipStream_t stream) {
    const float* x        = (const float*)d_in[0];
    const float* values   = (const float*)d_in[1];
    const int*   row_offs = (const int*)d_in[2];
    const int*   col_idx  = (const int*)d_in[3];
    float* y = (float*)d_out;

    const int nnz  = in_sizes[1];
    const int rows = in_sizes[2] - 1;              // 4096
    const int ntok = in_sizes[0] / IN_DIM;         // 8192
    const int kmax = nnz / rows + ((nnz % rows) ? 1 : 0);   // 41

    int ng = (kmax + 3) / 4;                       // k-groups of 4
    if (ng & 1) ++ng;                              // even for 2x-unrolled pipeline
    const int kalloc = (ng + 2) * 4;               // +2 zero groups for prefetch

    dim3 grid(ntok / TOKS), block(TPB);
    const size_t ell_bytes = (size_t)kalloc * OUT_DIM * sizeof(uint32_t);
    if (ws_size >= ell_bytes) {
        uint32_t* ell = (uint32_t*)d_ws;
        const int nthr = OUT_DIM * kalloc;
        build_ell<<<dim3((nthr + 255) / 256), dim3(256), 0, stream>>>(
            values, row_offs, col_idx, ell, kalloc);
        spmm_ell<<<grid, block, 0, stream>>>(x, ell, y, ng);
    } else {
        spmm_csr<<<grid, block, 0, stream>>>(x, values, row_offs, col_idx, y);
    }
}

// Round 3
// 126.275 us; speedup vs baseline: 1.5145x; 1.0041x over previous
//
#include <hip/hip_runtime.h>
#include <stdint.h>

#define IN_DIM   4096
#define OUT_DIM  4096
#define TPB      512
#define TOKS     8        // tokens per block; LDS = 4 bf16x2 pairs per column

// pack two fp32 -> bf16x2 dword (lo16 = a, hi16 = b), round-to-nearest-even
__device__ __forceinline__ uint32_t pack_bf16x2(float a, float b) {
    uint32_t ua = __float_as_uint(a);
    uint32_t ub = __float_as_uint(b);
    ua = (ua + 0x7fffu + ((ua >> 16) & 1u)) >> 16;
    ub = (ub + 0x7fffu + ((ub >> 16) & 1u)) & 0xffff0000u;
    return ub | ua;
}

// Stage 8 tokens of x (fp32, [token][IN_DIM]) into LDS as bf16x2, column-major:
// xs[col*4 + pair]; pair p holds tokens (2p, 2p+1).
// Per-lane write rotation keeps staging writes ~2-way banked (free).
__device__ __forceinline__ void stage_x_tile(const float* __restrict__ x,
                                             size_t tb, uint32_t* xs, int tid) {
    const int lane = tid & 63;
    const int wave = tid >> 6;          // 0..7
    const int tp   = lane >> 4;         // token pair 0..3
    const int rot  = (lane >> 1) & 3;   // write-order rotation
    const float* xa = x + (tb + 2 * (size_t)tp) * IN_DIM;
    const float* xb = xa + IN_DIM;
    #pragma unroll
    for (int it = 0; it < IN_DIM / 4 / 128; ++it) {   // 8 iterations
        const int c4 = (lane & 15) + 16 * wave + 128 * it;   // float4 column group
        const float4 a = *reinterpret_cast<const float4*>(xa + 4 * c4);
        const float4 b = *reinterpret_cast<const float4*>(xb + 4 * c4);
        const uint32_t d0 = pack_bf16x2(a.x, b.x);
        const uint32_t d1 = pack_bf16x2(a.y, b.y);
        const uint32_t d2 = pack_bf16x2(a.z, b.z);
        const uint32_t d3 = pack_bf16x2(a.w, b.w);
        // branchless rotate-left by rot (no runtime array indexing -> no scratch)
        const uint32_t t0 = (rot & 2) ? d2 : d0;
        const uint32_t t1 = (rot & 2) ? d3 : d1;
        const uint32_t t2 = (rot & 2) ? d0 : d2;
        const uint32_t t3 = (rot & 2) ? d1 : d3;
        const uint32_t u0 = (rot & 1) ? t1 : t0;
        const uint32_t u1 = (rot & 1) ? t2 : t1;
        const uint32_t u2 = (rot & 1) ? t3 : t2;
        const uint32_t u3 = (rot & 1) ? t0 : t3;
        const int cb = 4 * c4;
        xs[(cb + ((0 + rot) & 3)) * 4 + tp] = u0;
        xs[(cb + ((1 + rot) & 3)) * 4 + tp] = u1;
        xs[(cb + ((2 + rot) & 3)) * 4 + tp] = u2;
        xs[(cb + ((3 + rot) & 3)) * 4 + tp] = u3;
    }
}

// ELL metadata: ell[k*OUT_DIM + r] = (bf16(values) << 16) | col ; zero padded.
// One thread per (r, k) element.
__global__ void build_ell(const float* __restrict__ values,
                          const int* __restrict__ row_offs,
                          const int* __restrict__ col_idx,
                          uint32_t* __restrict__ ell, int kalloc) {
    const int idx = blockIdx.x * blockDim.x + threadIdx.x;
    const int r = idx & (OUT_DIM - 1);
    const int k = idx >> 12;            // log2(OUT_DIM)
    if (k >= kalloc) return;
    const int beg = row_offs[r];
    const int end = row_offs[r + 1];
    uint32_t u = 0;
    if (beg + k < end) {
        const uint32_t c = (uint32_t)col_idx[beg + k];
        uint32_t vb = __float_as_uint(values[beg + k]);
        vb = (vb + 0x7fffu + ((vb >> 16) & 1u)) & 0xffff0000u;
        u = vb | c;
    }
    ell[(size_t)k * OUT_DIM + r] = u;
}

// 8 MACs from one bf16x2-packed uint4 (8 tokens) against value e
// (value used with col bits in mantissa tail: rel err < 2^-11).
#define FMA8(E, D)                                                    \
    do {                                                              \
        const float v_ = __uint_as_float(E);                          \
        acc0 = fmaf(v_, __uint_as_float((D).x << 16), acc0);          \
        acc1 = fmaf(v_, __uint_as_float((D).x & 0xffff0000u), acc1);  \
        acc2 = fmaf(v_, __uint_as_float((D).y << 16), acc2);          \
        acc3 = fmaf(v_, __uint_as_float((D).y & 0xffff0000u), acc3);  \
        acc4 = fmaf(v_, __uint_as_float((D).z << 16), acc4);          \
        acc5 = fmaf(v_, __uint_as_float((D).z & 0xffff0000u), acc5);  \
        acc6 = fmaf(v_, __uint_as_float((D).w << 16), acc6);          \
        acc7 = fmaf(v_, __uint_as_float((D).w & 0xffff0000u), acc7);  \
    } while (0)

#define GATH(D, E) (D) = xs4[(E) & 0xffffu]

__global__ __launch_bounds__(TPB, 4)
void spmm_ell(const float* __restrict__ x, const uint32_t* __restrict__ ell,
              float* __restrict__ y, int ng) {
    __shared__ __align__(16) uint32_t xs[IN_DIM * (TOKS / 2)];   // 64 KB
    const int tid  = threadIdx.x;
    const size_t tb = (size_t)blockIdx.x * TOKS;

    stage_x_tile(x, tb, xs, tid);
    __syncthreads();
    const uint4* xs4 = reinterpret_cast<const uint4*>(xs);

    #pragma unroll 1
    for (int chunk = 0; chunk < OUT_DIM / TPB; ++chunk) {
        const int r = chunk * TPB + tid;
        float acc0 = 0.f, acc1 = 0.f, acc2 = 0.f, acc3 = 0.f;
        float acc4 = 0.f, acc5 = 0.f, acc6 = 0.f, acc7 = 0.f;
        const uint32_t* ep = ell + r;

        // ---- 2-deep software pipeline over k-groups of 4 (ng is even) ----
        // prologue: group0 -> (eA, dA), group1 -> eB
        uint32_t eA0 = ep[0 * (size_t)OUT_DIM], eA1 = ep[1 * (size_t)OUT_DIM];
        uint32_t eA2 = ep[2 * (size_t)OUT_DIM], eA3 = ep[3 * (size_t)OUT_DIM];
        uint4 dA0, dA1, dA2, dA3;
        GATH(dA0, eA0); GATH(dA1, eA1); GATH(dA2, eA2); GATH(dA3, eA3);
        uint32_t eB0 = ep[4 * (size_t)OUT_DIM], eB1 = ep[5 * (size_t)OUT_DIM];
        uint32_t eB2 = ep[6 * (size_t)OUT_DIM], eB3 = ep[7 * (size_t)OUT_DIM];
        uint4 dB0, dB1, dB2, dB3;
        const uint32_t* epn = ep + 8 * (size_t)OUT_DIM;

        #pragma unroll 1
        for (int g = 0; g < ng; g += 2) {
            // step g: compute (eA,dA); gather d for g+1 from eB; prefetch e(g+2)
            const uint32_t tA0 = epn[0 * (size_t)OUT_DIM], tA1 = epn[1 * (size_t)OUT_DIM];
            const uint32_t tA2 = epn[2 * (size_t)OUT_DIM], tA3 = epn[3 * (size_t)OUT_DIM];
            GATH(dB0, eB0); GATH(dB1, eB1); GATH(dB2, eB2); GATH(dB3, eB3);
            FMA8(eA0, dA0); FMA8(eA1, dA1); FMA8(eA2, dA2); FMA8(eA3, dA3);
            epn += 4 * (size_t)OUT_DIM;

            // step g+1: compute (eB,dB); gather d(g+2) from tA; prefetch e(g+3)
            const uint32_t tB0 = epn[0 * (size_t)OUT_DIM], tB1 = epn[1 * (size_t)OUT_DIM];
            const uint32_t tB2 = epn[2 * (size_t)OUT_DIM], tB3 = epn[3 * (size_t)OUT_DIM];
            GATH(dA0, tA0); GATH(dA1, tA1); GATH(dA2, tA2); GATH(dA3, tA3);
            FMA8(eB0, dB0); FMA8(eB1, dB1); FMA8(eB2, dB2); FMA8(eB3, dB3);
            epn += 4 * (size_t)OUT_DIM;

            eA0 = tA0; eA1 = tA1; eA2 = tA2; eA3 = tA3;   // e(g+2), its d in dA
            eB0 = tB0; eB1 = tB1; eB2 = tB2; eB3 = tB3;   // e(g+3)
        }

        y[(tb + 0) * OUT_DIM + r] = acc0;
        y[(tb + 1) * OUT_DIM + r] = acc1;
        y[(tb + 2) * OUT_DIM + r] = acc2;
        y[(tb + 3) * OUT_DIM + r] = acc3;
        y[(tb + 4) * OUT_DIM + r] = acc4;
        y[(tb + 5) * OUT_DIM + r] = acc5;
        y[(tb + 6) * OUT_DIM + r] = acc6;
        y[(tb + 7) * OUT_DIM + r] = acc7;
    }
}

// Fallback if d_ws too small for ELL: direct CSR (fp32 values).
__global__ __launch_bounds__(TPB, 4)
void spmm_csr(const float* __restrict__ x, const float* __restrict__ values,
              const int* __restrict__ row_offs, const int* __restrict__ col_idx,
              float* __restrict__ y) {
    __shared__ __align__(16) uint32_t xs[IN_DIM * (TOKS / 2)];
    const int tid  = threadIdx.x;
    const size_t tb = (size_t)blockIdx.x * TOKS;

    stage_x_tile(x, tb, xs, tid);
    __syncthreads();
    const uint4* xs4 = reinterpret_cast<const uint4*>(xs);

    #pragma unroll 1
    for (int chunk = 0; chunk < OUT_DIM / TPB; ++chunk) {
        const int r = chunk * TPB + tid;
        float acc0 = 0.f, acc1 = 0.f, acc2 = 0.f, acc3 = 0.f;
        float acc4 = 0.f, acc5 = 0.f, acc6 = 0.f, acc7 = 0.f;
        int k = row_offs[r];
        const int ke = row_offs[r + 1];
        for (; k < ke; ++k) {
            const uint32_t e = __float_as_uint(values[k]);
            const uint4 d = xs4[(uint32_t)col_idx[k]];
            FMA8(e, d);
        }
        y[(tb + 0) * OUT_DIM + r] = acc0;
        y[(tb + 1) * OUT_DIM + r] = acc1;
        y[(tb + 2) * OUT_DIM + r] = acc2;
        y[(tb + 3) * OUT_DIM + r] = acc3;
        y[(tb + 4) * OUT_DIM + r] = acc4;
        y[(tb + 5) * OUT_DIM + r] = acc5;
        y[(tb + 6) * OUT_DIM + r] = acc6;
        y[(tb + 7) * OUT_DIM + r] = acc7;
    }
}

extern "C" void kernel_launch(void* const* d_in, const int* in_sizes, int n_in,
                              void* d_out, int out_size, void* d_ws, size_t ws_size,
                              hipStream_t stream) {
    const float* x        = (const float*)d_in[0];
    const float* values   = (const float*)d_in[1];
    const int*   row_offs = (const int*)d_in[2];
    const int*   col_idx  = (const int*)d_in[3];
    float* y = (float*)d_out;

    const int nnz  = in_sizes[1];
    const int rows = in_sizes[2] - 1;              // 4096
    const int ntok = in_sizes[0] / IN_DIM;         // 8192
    const int kmax = nnz / rows + ((nnz % rows) ? 1 : 0);   // 41

    int ng = (kmax + 3) / 4;                       // k-groups of 4
    if (ng & 1) ++ng;                              // even for 2x-unrolled pipeline
    const int kalloc = (ng + 2) * 4;               // +2 zero groups for prefetch

    dim3 grid(ntok / TOKS), block(TPB);
    const size_t ell_bytes = (size_t)kalloc * OUT_DIM * sizeof(uint32_t);
    if (ws_size >= ell_bytes) {
        uint32_t* ell = (uint32_t*)d_ws;
        const int nthr = OUT_DIM * kalloc;
        build_ell<<<dim3((nthr + 255) / 256), dim3(256), 0, stream>>>(
            values, row_offs, col_idx, ell, kalloc);
        spmm_ell<<<grid, block, 0, stream>>>(x, ell, y, ng);
    } else {
        spmm_csr<<<grid, block, 0, stream>>>(x, values, row_offs, col_idx, y);
    }
}